// Round 13
// baseline (27.350 us; speedup 1.0000x reference)
//
#include <hip/hip_runtime.h>
#include <hip/hip_fp16.h>

// SurfEval: B=8, M=128, N=128, ctrl 4ch, P=Q=3, OUT=512
// ctrl_pts : (8,128,128,4) f32; Nu/Nv: (512,512,4) f32; spans: (512,512) i32 in [3,127]
// out : (8,512,512,3) f32 = sw[...,:3]/sw[...,3:]
//
// Round-13: r12 compute (fp16 LDS net + pk_fma inner, f32 outer), but each
// (chunk,batch) is served by TWO blocks split by us3 (<62 vs >=62). Each
// holds only its 65/66-row half-net (65-68 KB LDS) -> 2 blocks/CU = 32
// resident waves (vs 16) for pipe overlap. Streams read by both halves
// (L2-shared, XCD-pinned); lanes exec-masked by membership. Next-iter
// stream prefetch in registers.

#define OUTD 512
#define UVN  (OUTD * OUTD)   // 262144
#define MD   128
#define ND   128
#define BD   8
#define MN   (MD * ND)       // 16384
#define TPB  1024
#define NCHUNK 32
#define UVPC (UVN / NCHUNK)  // 8192
#define ITERS (UVPC / TPB)   // 8
#define USPLIT 62            // h=0: us3 in [0,61]; h=1: us3 in [62,124]
#define ROWS1  66            // max rows per half (h=1: rows 62..127)

__device__ __forceinline__ uint2 pack4h(const float4 c) {
    __half2 h01 = __floats2half2_rn(c.x, c.y);
    __half2 h23 = __floats2half2_rn(c.z, c.w);
    uint2 u;
    u.x = *reinterpret_cast<unsigned int*>(&h01);
    u.y = *reinterpret_cast<unsigned int*>(&h23);
    return u;
}

__global__ __launch_bounds__(TPB, 8) void surfeval_r13_kernel(
    const float4* __restrict__ ctrl,   // (b, m*n) float4
    const float4* __restrict__ Nu4,
    const float4* __restrict__ Nv4,
    const int* __restrict__ uspan,
    const int* __restrict__ vspan,
    float* __restrict__ out)
{
    __shared__ uint2 cl[ROWS1 * ND];     // 67.6 KB: this block's half-net

    // bid = (c&7) | (g<<3), g = b + 8*h + 16*(c>>3)
    const int bid = blockIdx.x;
    const int g   = bid >> 3;
    const int b   = g & 7;
    const int h   = (g >> 3) & 1;
    const int c   = (bid & 7) | ((g >> 4) << 3);
    const int tid = threadIdx.x;

    const int row0  = h ? USPLIT : 0;               // first staged row
    const int nrows = h ? (MD - USPLIT) : (USPLIT + 3);  // 66 / 65
    const int nel   = nrows * ND;

    // ---- stage half-net: f32 -> fp16, dense
    const float4* cb = ctrl + (size_t)b * MN + row0 * ND;
    for (int i = tid; i < nel; i += TPB)
        cl[i] = pack4h(cb[i]);
    __syncthreads();

    const char* ldsb = (const char*)cl;

    // ---- prefetch iteration 0 streams
    int uv  = c * UVPC + tid;
    int us3 = uspan[uv] - 3;
    int vs3 = vspan[uv] - 3;
    float4 nu = Nu4[uv];
    float4 nv = Nv4[uv];

    #pragma unroll 1
    for (int it = 0; it < ITERS; ++it) {
        const int   uvC  = uv;
        const int   us3C = us3, vs3C = vs3;
        const float4 nuC = nu,  nvC  = nv;

        if (it + 1 < ITERS) {               // prefetch next iter (all lanes)
            const int uvN = uvC + TPB;
            us3 = uspan[uvN] - 3;
            vs3 = vspan[uvN] - 3;
            nu  = Nu4[uvN];
            nv  = Nv4[uvN];
            uv  = uvN;
        }

        const bool active = h ? (us3C >= USPLIT) : (us3C < USPLIT);
        if (active) {
            __half2 nus[4];
            nus[0] = __float2half2_rn(nuC.x);
            nus[1] = __float2half2_rn(nuC.y);
            nus[2] = __float2half2_rn(nuC.z);
            nus[3] = __float2half2_rn(nuC.w);
            const float nvL[4] = {nvC.x, nvC.y, nvC.z, nvC.w};

            const int base = ((us3C - row0) * ND + vs3C) * 8;  // LDS byte offset
            __half2 t01[4], t23[4];
            #pragma unroll
            for (int r = 0; r < 4; ++r) {
                t01[r] = __float2half2_rn(0.f);
                t23[r] = __float2half2_rn(0.f);
            }
            #pragma unroll
            for (int l = 0; l < 4; ++l) {
                #pragma unroll
                for (int r = 0; r < 4; ++r) {
                    const uint2 hh = *(const uint2*)(ldsb + base + l * (ND * 8) + r * 8);
                    t01[r] = __hfma2(nus[l], *(const __half2*)(&hh.x), t01[r]);
                    t23[r] = __hfma2(nus[l], *(const __half2*)(&hh.y), t23[r]);
                }
            }

            float ax = 0.f, ay = 0.f, az = 0.f, aw = 0.f;
            #pragma unroll
            for (int r = 0; r < 4; ++r) {
                const float2 xy = __half22float2(t01[r]);
                const float2 zw = __half22float2(t23[r]);
                ax = fmaf(nvL[r], xy.x, ax);
                ay = fmaf(nvL[r], xy.y, ay);
                az = fmaf(nvL[r], zw.x, az);
                aw = fmaf(nvL[r], zw.y, aw);
            }

            const float inv = 1.0f / aw;
            float* o = out + ((size_t)b * UVN + uvC) * 3;
            o[0] = ax * inv;
            o[1] = ay * inv;
            o[2] = az * inv;
        }
    }
}

extern "C" void kernel_launch(void* const* d_in, const int* in_sizes, int n_in,
                              void* d_out, int out_size, void* d_ws, size_t ws_size,
                              hipStream_t stream) {
    const float* ctrl  = (const float*)d_in[0];
    const float* Nu    = (const float*)d_in[1];
    const float* Nv    = (const float*)d_in[2];
    const int*   uspan = (const int*)d_in[3];
    const int*   vspan = (const int*)d_in[4];
    float* out = (float*)d_out;

    surfeval_r13_kernel<<<NCHUNK * BD * 2, TPB, 0, stream>>>(
        (const float4*)ctrl, (const float4*)Nu, (const float4*)Nv,
        uspan, vspan, out);
}

// Round 14
// 24.074 us; speedup vs baseline: 1.1361x; 1.1361x over previous
//
#include <hip/hip_runtime.h>
#include <hip/hip_fp16.h>

// SurfEval: B=8, M=128, N=128, ctrl 4ch, P=Q=3, OUT=512
// ctrl_pts : (8,128,128,4) f32; Nu/Nv: (512,512,4) f32; spans: (512,512) i32 in [3,127]
// out : (8,512,512,3) f32 = sw[...,:3]/sw[...,3:]
//
// Round-14: r12 structure (one batch's net as fp16 in 128 KB LDS, XCD-swizzled
// chunk x batch grid, pk_fma inner / f32 outer math, dense streams+stores),
// plus 2-uv-per-thread ILP: both points' 32 ds_read_b64 issue before the FMA
// blocks, and the next iteration's streams are register-prefetched. LDS
// footprint and per-uv instruction count unchanged; outstanding-op depth 2x.

#define OUTD 512
#define UVN  (OUTD * OUTD)   // 262144
#define MD   128
#define ND   128
#define BD   8
#define MN   (MD * ND)       // 16384
#define TPB  1024
#define NCHUNK 32
#define UVPC (UVN / NCHUNK)  // 8192
#define ITER2 (UVPC / (2 * TPB))  // 4 iterations, 2 uv/thread each

__device__ __forceinline__ uint2 pack4h(const float4 c) {
    __half2 h01 = __floats2half2_rn(c.x, c.y);
    __half2 h23 = __floats2half2_rn(c.z, c.w);
    uint2 u;
    u.x = *reinterpret_cast<unsigned int*>(&h01);
    u.y = *reinterpret_cast<unsigned int*>(&h23);
    return u;
}

struct StreamRegs {
    int us3, vs3;
    float4 nu, nv;
};

__device__ __forceinline__ StreamRegs load_stream(
    const int* __restrict__ uspan, const int* __restrict__ vspan,
    const float4* __restrict__ Nu4, const float4* __restrict__ Nv4, int uv)
{
    StreamRegs s;
    s.us3 = uspan[uv] - 3;
    s.vs3 = vspan[uv] - 3;
    s.nu  = Nu4[uv];
    s.nv  = Nv4[uv];
    return s;
}

__global__ __launch_bounds__(TPB) void surfeval_r14_kernel(
    const float4* __restrict__ ctrl,   // (b, m*n) float4
    const float4* __restrict__ Nu4,
    const float4* __restrict__ Nv4,
    const int* __restrict__ uspan,
    const int* __restrict__ vspan,
    float* __restrict__ out)
{
    __shared__ uint2 cl[MN];             // 128 KB fp16 net of this block's batch

    const int bid = blockIdx.x;          // bid = (c&7) + 8*(b + 8*(c>>3))
    const int b   = (bid >> 3) & 7;
    const int c   = (bid & 7) | ((bid >> 6) << 3);
    const int tid = threadIdx.x;

    // ---- stage batch b: 256 KB f32 -> 128 KB fp16 LDS (dense)
    const float4* cb = ctrl + (size_t)b * MN;
    #pragma unroll
    for (int i = 0; i < MN / TPB; ++i) {
        const int idx = i * TPB + tid;
        cl[idx] = pack4h(cb[idx]);
    }
    __syncthreads();

    const char* ldsb = (const char*)cl;
    float* const outb = out + (size_t)b * UVN * 3;

    int uvA = c * UVPC + tid;            // pair: uvA, uvA + TPB
    StreamRegs sA = load_stream(uspan, vspan, Nu4, Nv4, uvA);
    StreamRegs sB = load_stream(uspan, vspan, Nu4, Nv4, uvA + TPB);

    #pragma unroll 1
    for (int it = 0; it < ITER2; ++it) {
        const int uvA_c = uvA;
        const StreamRegs a = sA, bb = sB;

        if (it + 1 < ITER2) {            // register-prefetch next iteration
            uvA += 2 * TPB;
            sA = load_stream(uspan, vspan, Nu4, Nv4, uvA);
            sB = load_stream(uspan, vspan, Nu4, Nv4, uvA + TPB);
        }

        // ---- issue ALL 32 LDS reads (both points) up front
        const int baseA = (a.us3  * ND + a.vs3)  * 8;
        const int baseB = (bb.us3 * ND + bb.vs3) * 8;
        uint2 hA[4][4], hB[4][4];
        #pragma unroll
        for (int l = 0; l < 4; ++l) {
            #pragma unroll
            for (int r = 0; r < 4; ++r) {
                hA[l][r] = *(const uint2*)(ldsb + baseA + l * (ND * 8) + r * 8);
                hB[l][r] = *(const uint2*)(ldsb + baseB + l * (ND * 8) + r * 8);
            }
        }

        // ---- compute A
        {
            __half2 nus[4];
            nus[0] = __float2half2_rn(a.nu.x);
            nus[1] = __float2half2_rn(a.nu.y);
            nus[2] = __float2half2_rn(a.nu.z);
            nus[3] = __float2half2_rn(a.nu.w);
            const float nvL[4] = {a.nv.x, a.nv.y, a.nv.z, a.nv.w};
            __half2 t01[4], t23[4];
            #pragma unroll
            for (int r = 0; r < 4; ++r) {
                t01[r] = __float2half2_rn(0.f);
                t23[r] = __float2half2_rn(0.f);
            }
            #pragma unroll
            for (int l = 0; l < 4; ++l) {
                #pragma unroll
                for (int r = 0; r < 4; ++r) {
                    t01[r] = __hfma2(nus[l], *(const __half2*)(&hA[l][r].x), t01[r]);
                    t23[r] = __hfma2(nus[l], *(const __half2*)(&hA[l][r].y), t23[r]);
                }
            }
            float ax = 0.f, ay = 0.f, az = 0.f, aw = 0.f;
            #pragma unroll
            for (int r = 0; r < 4; ++r) {
                const float2 xy = __half22float2(t01[r]);
                const float2 zw = __half22float2(t23[r]);
                ax = fmaf(nvL[r], xy.x, ax);
                ay = fmaf(nvL[r], xy.y, ay);
                az = fmaf(nvL[r], zw.x, az);
                aw = fmaf(nvL[r], zw.y, aw);
            }
            const float inv = 1.0f / aw;
            float* o = outb + (size_t)uvA_c * 3;
            o[0] = ax * inv; o[1] = ay * inv; o[2] = az * inv;
        }

        // ---- compute B
        {
            __half2 nus[4];
            nus[0] = __float2half2_rn(bb.nu.x);
            nus[1] = __float2half2_rn(bb.nu.y);
            nus[2] = __float2half2_rn(bb.nu.z);
            nus[3] = __float2half2_rn(bb.nu.w);
            const float nvL[4] = {bb.nv.x, bb.nv.y, bb.nv.z, bb.nv.w};
            __half2 t01[4], t23[4];
            #pragma unroll
            for (int r = 0; r < 4; ++r) {
                t01[r] = __float2half2_rn(0.f);
                t23[r] = __float2half2_rn(0.f);
            }
            #pragma unroll
            for (int l = 0; l < 4; ++l) {
                #pragma unroll
                for (int r = 0; r < 4; ++r) {
                    t01[r] = __hfma2(nus[l], *(const __half2*)(&hB[l][r].x), t01[r]);
                    t23[r] = __hfma2(nus[l], *(const __half2*)(&hB[l][r].y), t23[r]);
                }
            }
            float ax = 0.f, ay = 0.f, az = 0.f, aw = 0.f;
            #pragma unroll
            for (int r = 0; r < 4; ++r) {
                const float2 xy = __half22float2(t01[r]);
                const float2 zw = __half22float2(t23[r]);
                ax = fmaf(nvL[r], xy.x, ax);
                ay = fmaf(nvL[r], xy.y, ay);
                az = fmaf(nvL[r], zw.x, az);
                aw = fmaf(nvL[r], zw.y, aw);
            }
            const float inv = 1.0f / aw;
            float* o = outb + (size_t)(uvA_c + TPB) * 3;
            o[0] = ax * inv; o[1] = ay * inv; o[2] = az * inv;
        }
    }
}

extern "C" void kernel_launch(void* const* d_in, const int* in_sizes, int n_in,
                              void* d_out, int out_size, void* d_ws, size_t ws_size,
                              hipStream_t stream) {
    const float* ctrl  = (const float*)d_in[0];
    const float* Nu    = (const float*)d_in[1];
    const float* Nv    = (const float*)d_in[2];
    const int*   uspan = (const int*)d_in[3];
    const int*   vspan = (const int*)d_in[4];
    float* out = (float*)d_out;

    surfeval_r14_kernel<<<NCHUNK * BD, TPB, 0, stream>>>(
        (const float4*)ctrl, (const float4*)Nu, (const float4*)Nv,
        uspan, vspan, out);
}